// Round 1
// baseline (641.990 us; speedup 1.0000x reference)
//
#include <hip/hip_runtime.h>
#include <hip/hip_bf16.h>

typedef __attribute__((ext_vector_type(4))) float f32x4;
typedef __attribute__((ext_vector_type(8))) short bf16x8;

#define NN 131072      // minibatch nodes
#define TT 100000      // rows per featured table
#define DD 512         // raw feature dim
#define EE 256         // embedding size

__device__ inline ushort f2bf(float f) {
    union { float f; unsigned u; } x; x.f = f;
    unsigned r = x.u + 0x7fffu + ((x.u >> 16) & 1u);
    return (ushort)(r >> 16);
}

// ---------------- compact: build row lists for types 0 and 1 ----------------
__global__ void compact_kernel(const int* __restrict__ tids, int* __restrict__ cnt,
                               int* __restrict__ l0, int* __restrict__ l1) {
    int i = blockIdx.x * 256 + threadIdx.x;
    if (i >= NN) return;
    int t = tids[i];
    if (t == 0)      { int p = atomicAdd(&cnt[0], 1); l0[p] = i; }
    else if (t == 1) { int p = atomicAdd(&cnt[1], 1); l1[p] = i; }
}

// ---------------- prep: W (D x E, f32) -> Wt (E x D, bf16) ----------------
__global__ void prep_w_kernel(const float* __restrict__ W0, const float* __restrict__ W1,
                              ushort* __restrict__ Wt0, ushort* __restrict__ Wt1) {
    int gid = blockIdx.x * 256 + threadIdx.x;   // 65536 total = 2 * 512 * 64
    int t = gid >> 15;
    int rem = gid & 32767;
    int d = rem >> 6, eg = rem & 63;
    const float* W = t ? W1 : W0;
    ushort* Wt = t ? Wt1 : Wt0;
    f32x4 v = *(const f32x4*)(W + d * EE + eg * 4);
#pragma unroll
    for (int j = 0; j < 4; ++j)
        Wt[(size_t)(eg * 4 + j) * DD + d] = f2bf(v[j]);
}

// ---------------- embedding gather for tids >= 2 ----------------
__global__ void emb_gather_kernel(const int* __restrict__ ids, const int* __restrict__ tids,
                                  const float* __restrict__ emb, float* __restrict__ out) {
    int gid = blockIdx.x * 256 + threadIdx.x;   // N*64 total, float4 granularity
    int i = gid >> 6, j = gid & 63;
    if (tids[i] >= 2) {
        ((f32x4*)out)[(size_t)i * 64 + j] = ((const f32x4*)emb)[(size_t)ids[i] * 64 + j];
    }
}

// ---------------- gathered-A GEMM: out[list[r]] = bf16(feats[type_ids[list[r]]]) @ W ----
// BM=128, BN=256 (full E), BK=64. 512 threads = 8 waves (4 M x 2 N).
__global__ __launch_bounds__(512) void gemm_gather_kernel(
    const int* __restrict__ list, const int* __restrict__ cntp,
    const int* __restrict__ type_ids, const float* __restrict__ feats,
    const ushort* __restrict__ Wt, float* __restrict__ out) {
    const int cnt = *cntp;
    const int row0 = blockIdx.x * 128;
    if (row0 >= cnt) return;

    __shared__ char Alds[128 * 64 * 2];   // 16 KB, byte addr row*128 + k*2, XOR swizzled
    __shared__ char Blds[256 * 64 * 2];   // 32 KB, byte addr col*128 + k*2, XOR swizzled

    const int tid = threadIdx.x;
    const int lane = tid & 63, wid = tid >> 6;
    const int wr = wid >> 1, wc = wid & 1;      // wave tile: 32 rows x 128 cols
    const int ln15 = lane & 15, lq = lane >> 4;

    // A gather setup: thread = (row = tid>>2) x (seg = tid&3, 16 f32 each)
    const int ar = tid >> 2, aseg = tid & 3;
    const int rg = row0 + ar;
    int arow = 0;
    if (rg < cnt) arow = type_ids[list[rg]];
    const float* asrc = feats + (size_t)arow * DD + aseg * 16;
    int aw0 = ar * 128 + aseg * 32;
    int aw1 = aw0 + 16;
    aw0 ^= (ar & 7) << 4;
    aw1 ^= (ar & 7) << 4;

    f32x4 acc[2][8] = {};

    for (int k0 = 0; k0 < DD; k0 += 64) {
        // ---- stage A: 16 f32 -> 16 bf16 -> 2x ds_write_b128
        const f32x4* ap = (const f32x4*)(asrc + k0);
        f32x4 v0 = ap[0], v1 = ap[1], v2 = ap[2], v3 = ap[3];
        bf16x8 h0, h1;
        h0[0] = (short)f2bf(v0[0]); h0[1] = (short)f2bf(v0[1]);
        h0[2] = (short)f2bf(v0[2]); h0[3] = (short)f2bf(v0[3]);
        h0[4] = (short)f2bf(v1[0]); h0[5] = (short)f2bf(v1[1]);
        h0[6] = (short)f2bf(v1[2]); h0[7] = (short)f2bf(v1[3]);
        h1[0] = (short)f2bf(v2[0]); h1[1] = (short)f2bf(v2[1]);
        h1[2] = (short)f2bf(v2[2]); h1[3] = (short)f2bf(v2[3]);
        h1[4] = (short)f2bf(v3[0]); h1[5] = (short)f2bf(v3[1]);
        h1[6] = (short)f2bf(v3[2]); h1[7] = (short)f2bf(v3[3]);
        *(bf16x8*)(Alds + aw0) = h0;
        *(bf16x8*)(Alds + aw1) = h1;

        // ---- stage B: 256 cols x 64 k bf16 from Wt (already transposed)
#pragma unroll
        for (int p = 0; p < 4; ++p) {
            int c = p * 512 + tid;
            int col = c >> 3, seg = c & 7;
            bf16x8 bv = *(const bf16x8*)(Wt + col * DD + k0 + seg * 8);
            int addr = col * 128 + seg * 16;
            addr ^= (col & 7) << 4;
            *(bf16x8*)(Blds + addr) = bv;
        }
        __syncthreads();

        // ---- compute: 2 k-halves x (2 M-frags x 8 N-frags)
#pragma unroll
        for (int kh = 0; kh < 2; ++kh) {
            const int kb = kh * 64 + lq * 16;
            int ra0 = wr * 32 + ln15;
            int a0addr = (ra0 * 128 + kb) ^ ((ra0 & 7) << 4);
            int ra1 = ra0 + 16;
            int a1addr = (ra1 * 128 + kb) ^ ((ra1 & 7) << 4);
            bf16x8 a0 = *(const bf16x8*)(Alds + a0addr);
            bf16x8 a1 = *(const bf16x8*)(Alds + a1addr);
#pragma unroll
            for (int ni = 0; ni < 8; ++ni) {
                int col = wc * 128 + ni * 16 + ln15;
                int baddr = (col * 128 + kb) ^ ((col & 7) << 4);
                bf16x8 b = *(const bf16x8*)(Blds + baddr);
                acc[0][ni] = __builtin_amdgcn_mfma_f32_16x16x32_bf16(a0, b, acc[0][ni], 0, 0, 0);
                acc[1][ni] = __builtin_amdgcn_mfma_f32_16x16x32_bf16(a1, b, acc[1][ni], 0, 0, 0);
            }
        }
        __syncthreads();
    }

    // ---- epilogue: scatter rows to out[node]
#pragma unroll
    for (int mi = 0; mi < 2; ++mi) {
        int mbase = row0 + wr * 32 + mi * 16 + lq * 4;
#pragma unroll
        for (int rr = 0; rr < 4; ++rr) {
            int r = mbase + rr;
            if (r < cnt) {
                int nd = list[r];
                float* orow = out + (size_t)nd * EE + wc * 128 + ln15;
#pragma unroll
                for (int ni = 0; ni < 8; ++ni) orow[ni * 16] = acc[mi][ni][rr];
            }
        }
    }
}

extern "C" void kernel_launch(void* const* d_in, const int* in_sizes, int n_in,
                              void* d_out, int out_size, void* d_ws, size_t ws_size,
                              hipStream_t stream) {
    const int*   node_ids  = (const int*)d_in[0];
    const int*   node_tids = (const int*)d_in[1];
    const int*   type_ids  = (const int*)d_in[2];
    const float* feats0    = (const float*)d_in[3];
    const float* feats1    = (const float*)d_in[4];
    const float* W0        = (const float*)d_in[5];
    const float* W1        = (const float*)d_in[6];
    const float* node_emb  = (const float*)d_in[7];
    float* out = (float*)d_out;

    char* ws = (char*)d_ws;
    int* cnt = (int*)ws;                              // 16 B
    int* l0  = (int*)(ws + 16);                       // N ints
    int* l1  = (int*)(ws + 16 + 524288);              // N ints
    ushort* Wt0 = (ushort*)(ws + 16 + 2 * 524288);    // 256 KB
    ushort* Wt1 = Wt0 + DD * EE;                      // 256 KB

    hipMemsetAsync(cnt, 0, 16, stream);
    prep_w_kernel<<<256, 256, 0, stream>>>(W0, W1, Wt0, Wt1);
    compact_kernel<<<512, 256, 0, stream>>>(node_tids, cnt, l0, l1);
    emb_gather_kernel<<<32768, 256, 0, stream>>>(node_ids, node_tids, node_emb, out);
    gemm_gather_kernel<<<1024, 512, 0, stream>>>(l0, &cnt[0], type_ids, feats0, Wt0, out);
    gemm_gather_kernel<<<1024, 512, 0, stream>>>(l1, &cnt[1], type_ids, feats1, Wt1, out);
}

// Round 2
// 137.718 us; speedup vs baseline: 4.6616x; 4.6616x over previous
//
#include <hip/hip_runtime.h>
#include <hip/hip_bf16.h>

typedef __attribute__((ext_vector_type(4))) float f32x4;
typedef __attribute__((ext_vector_type(8))) short bf16x8;

#define NN 131072      // minibatch nodes
#define TT 100000      // rows per featured table
#define DD 512         // raw feature dim
#define EE 256         // embedding size

__device__ inline ushort f2bf(float f) {
    union { float f; unsigned u; } x; x.f = f;
    unsigned r = x.u + 0x7fffu + ((x.u >> 16) & 1u);
    return (ushort)(r >> 16);
}

// ---------------- compact: build row lists for types 0 and 1 ----------------
// Two-level aggregation: ballot+popc per wave, LDS per block, ONE atomic per
// block per type (was: per-thread divergent atomics -> 517 us of serialization).
__global__ void compact_kernel(const int* __restrict__ tids, int* __restrict__ cnt,
                               int* __restrict__ l0, int* __restrict__ l1) {
    const int i = blockIdx.x * 256 + threadIdx.x;   // grid is exact: 512*256 = NN
    const int t = tids[i];
    const int lane = threadIdx.x & 63, wid = threadIdx.x >> 6;
    unsigned long long b0 = __ballot(t == 0);
    unsigned long long b1 = __ballot(t == 1);
    __shared__ int w0[4], w1[4];
    __shared__ int base0, base1;
    if (lane == 0) { w0[wid] = __popcll(b0); w1[wid] = __popcll(b1); }
    __syncthreads();
    if (threadIdx.x == 0) {
        base0 = atomicAdd(&cnt[0], w0[0] + w0[1] + w0[2] + w0[3]);
        base1 = atomicAdd(&cnt[1], w1[0] + w1[1] + w1[2] + w1[3]);
    }
    __syncthreads();
    int p0 = 0, p1 = 0;
#pragma unroll
    for (int w = 0; w < 4; ++w) if (w < wid) { p0 += w0[w]; p1 += w1[w]; }
    const unsigned long long ltm = (1ull << lane) - 1ull;
    if (t == 0)      l0[base0 + p0 + __popcll(b0 & ltm)] = i;
    else if (t == 1) l1[base1 + p1 + __popcll(b1 & ltm)] = i;
}

// ---------------- prep: W (D x E, f32) -> Wt (E x D, bf16) ----------------
__global__ void prep_w_kernel(const float* __restrict__ W0, const float* __restrict__ W1,
                              ushort* __restrict__ Wt0, ushort* __restrict__ Wt1) {
    int gid = blockIdx.x * 256 + threadIdx.x;   // 65536 total = 2 * 512 * 64
    int t = gid >> 15;
    int rem = gid & 32767;
    int d = rem >> 6, eg = rem & 63;
    const float* W = t ? W1 : W0;
    ushort* Wt = t ? Wt1 : Wt0;
    f32x4 v = *(const f32x4*)(W + d * EE + eg * 4);
#pragma unroll
    for (int j = 0; j < 4; ++j)
        Wt[(size_t)(eg * 4 + j) * DD + d] = f2bf(v[j]);
}

// ---------------- embedding gather for tids >= 2 ----------------
__global__ void emb_gather_kernel(const int* __restrict__ ids, const int* __restrict__ tids,
                                  const float* __restrict__ emb, float* __restrict__ out) {
    int gid = blockIdx.x * 256 + threadIdx.x;   // N*64 total, float4 granularity
    int i = gid >> 6, j = gid & 63;
    if (tids[i] >= 2) {
        ((f32x4*)out)[(size_t)i * 64 + j] = ((const f32x4*)emb)[(size_t)ids[i] * 64 + j];
    }
}

// ---------------- gathered-A GEMM: out[list[r]] = bf16(feats[type_ids[list[r]]]) @ W ----
// BM=128, BN=256 (full E), BK=64. 512 threads = 8 waves (4 M x 2 N).
__global__ __launch_bounds__(512) void gemm_gather_kernel(
    const int* __restrict__ list, const int* __restrict__ cntp,
    const int* __restrict__ type_ids, const float* __restrict__ feats,
    const ushort* __restrict__ Wt, float* __restrict__ out) {
    const int cnt = *cntp;
    const int row0 = blockIdx.x * 128;
    if (row0 >= cnt) return;

    __shared__ char Alds[128 * 64 * 2];   // 16 KB, byte addr row*128 + k*2, XOR swizzled
    __shared__ char Blds[256 * 64 * 2];   // 32 KB, byte addr col*128 + k*2, XOR swizzled

    const int tid = threadIdx.x;
    const int lane = tid & 63, wid = tid >> 6;
    const int wr = wid >> 1, wc = wid & 1;      // wave tile: 32 rows x 128 cols
    const int ln15 = lane & 15, lq = lane >> 4;

    // A gather setup: thread = (row = tid>>2) x (seg = tid&3, 16 f32 each)
    const int ar = tid >> 2, aseg = tid & 3;
    const int rg = row0 + ar;
    int arow = 0;
    if (rg < cnt) arow = type_ids[list[rg]];
    const float* asrc = feats + (size_t)arow * DD + aseg * 16;
    int aw0 = ar * 128 + aseg * 32;
    int aw1 = aw0 + 16;
    aw0 ^= (ar & 7) << 4;
    aw1 ^= (ar & 7) << 4;

    f32x4 acc[2][8] = {};

    for (int k0 = 0; k0 < DD; k0 += 64) {
        // ---- stage A: 16 f32 -> 16 bf16 -> 2x ds_write_b128
        const f32x4* ap = (const f32x4*)(asrc + k0);
        f32x4 v0 = ap[0], v1 = ap[1], v2 = ap[2], v3 = ap[3];
        bf16x8 h0, h1;
        h0[0] = (short)f2bf(v0[0]); h0[1] = (short)f2bf(v0[1]);
        h0[2] = (short)f2bf(v0[2]); h0[3] = (short)f2bf(v0[3]);
        h0[4] = (short)f2bf(v1[0]); h0[5] = (short)f2bf(v1[1]);
        h0[6] = (short)f2bf(v1[2]); h0[7] = (short)f2bf(v1[3]);
        h1[0] = (short)f2bf(v2[0]); h1[1] = (short)f2bf(v2[1]);
        h1[2] = (short)f2bf(v2[2]); h1[3] = (short)f2bf(v2[3]);
        h1[4] = (short)f2bf(v3[0]); h1[5] = (short)f2bf(v3[1]);
        h1[6] = (short)f2bf(v3[2]); h1[7] = (short)f2bf(v3[3]);
        *(bf16x8*)(Alds + aw0) = h0;
        *(bf16x8*)(Alds + aw1) = h1;

        // ---- stage B: 256 cols x 64 k bf16 from Wt (already transposed)
#pragma unroll
        for (int p = 0; p < 4; ++p) {
            int c = p * 512 + tid;
            int col = c >> 3, seg = c & 7;
            bf16x8 bv = *(const bf16x8*)(Wt + col * DD + k0 + seg * 8);
            int addr = col * 128 + seg * 16;
            addr ^= (col & 7) << 4;
            *(bf16x8*)(Blds + addr) = bv;
        }
        __syncthreads();

        // ---- compute: 2 k-halves x (2 M-frags x 8 N-frags)
#pragma unroll
        for (int kh = 0; kh < 2; ++kh) {
            const int kb = kh * 64 + lq * 16;
            int ra0 = wr * 32 + ln15;
            int a0addr = (ra0 * 128 + kb) ^ ((ra0 & 7) << 4);
            int ra1 = ra0 + 16;
            int a1addr = (ra1 * 128 + kb) ^ ((ra1 & 7) << 4);
            bf16x8 a0 = *(const bf16x8*)(Alds + a0addr);
            bf16x8 a1 = *(const bf16x8*)(Alds + a1addr);
#pragma unroll
            for (int ni = 0; ni < 8; ++ni) {
                int col = wc * 128 + ni * 16 + ln15;
                int baddr = (col * 128 + kb) ^ ((col & 7) << 4);
                bf16x8 b = *(const bf16x8*)(Blds + baddr);
                acc[0][ni] = __builtin_amdgcn_mfma_f32_16x16x32_bf16(a0, b, acc[0][ni], 0, 0, 0);
                acc[1][ni] = __builtin_amdgcn_mfma_f32_16x16x32_bf16(a1, b, acc[1][ni], 0, 0, 0);
            }
        }
        __syncthreads();
    }

    // ---- epilogue: scatter rows to out[node]
#pragma unroll
    for (int mi = 0; mi < 2; ++mi) {
        int mbase = row0 + wr * 32 + mi * 16 + lq * 4;
#pragma unroll
        for (int rr = 0; rr < 4; ++rr) {
            int r = mbase + rr;
            if (r < cnt) {
                int nd = list[r];
                float* orow = out + (size_t)nd * EE + wc * 128 + ln15;
#pragma unroll
                for (int ni = 0; ni < 8; ++ni) orow[ni * 16] = acc[mi][ni][rr];
            }
        }
    }
}

extern "C" void kernel_launch(void* const* d_in, const int* in_sizes, int n_in,
                              void* d_out, int out_size, void* d_ws, size_t ws_size,
                              hipStream_t stream) {
    const int*   node_ids  = (const int*)d_in[0];
    const int*   node_tids = (const int*)d_in[1];
    const int*   type_ids  = (const int*)d_in[2];
    const float* feats0    = (const float*)d_in[3];
    const float* feats1    = (const float*)d_in[4];
    const float* W0        = (const float*)d_in[5];
    const float* W1        = (const float*)d_in[6];
    const float* node_emb  = (const float*)d_in[7];
    float* out = (float*)d_out;

    char* ws = (char*)d_ws;
    int* cnt = (int*)ws;                              // 16 B
    int* l0  = (int*)(ws + 16);                       // N ints
    int* l1  = (int*)(ws + 16 + 524288);              // N ints
    ushort* Wt0 = (ushort*)(ws + 16 + 2 * 524288);    // 256 KB
    ushort* Wt1 = Wt0 + DD * EE;                      // 256 KB

    hipMemsetAsync(cnt, 0, 16, stream);
    prep_w_kernel<<<256, 256, 0, stream>>>(W0, W1, Wt0, Wt1);
    compact_kernel<<<512, 256, 0, stream>>>(node_tids, cnt, l0, l1);
    emb_gather_kernel<<<32768, 256, 0, stream>>>(node_ids, node_tids, node_emb, out);
    gemm_gather_kernel<<<1024, 512, 0, stream>>>(l0, &cnt[0], type_ids, feats0, Wt0, out);
    gemm_gather_kernel<<<1024, 512, 0, stream>>>(l1, &cnt[1], type_ids, feats1, Wt1, out);
}

// Round 3
// 130.088 us; speedup vs baseline: 4.9351x; 1.0587x over previous
//
#include <hip/hip_runtime.h>
#include <hip/hip_bf16.h>

typedef __attribute__((ext_vector_type(4))) float f32x4;
typedef __attribute__((ext_vector_type(8))) short bf16x8;

#define NN 131072      // minibatch nodes
#define TT 100000      // rows per featured table
#define DD 512         // raw feature dim
#define EE 256         // embedding size

__device__ inline ushort f2bf(float f) {
    union { float f; unsigned u; } x; x.f = f;
    unsigned r = x.u + 0x7fffu + ((x.u >> 16) & 1u);
    return (ushort)(r >> 16);
}

// ---------------- compact: build row lists for types 0 and 1 ----------------
// Two-level aggregation: ballot+popc per wave, one atomic per block per type.
__global__ void compact_kernel(const int* __restrict__ tids, int* __restrict__ cnt,
                               int* __restrict__ l0, int* __restrict__ l1) {
    const int i = blockIdx.x * 256 + threadIdx.x;   // grid is exact: 512*256 = NN
    const int t = tids[i];
    const int lane = threadIdx.x & 63, wid = threadIdx.x >> 6;
    unsigned long long b0 = __ballot(t == 0);
    unsigned long long b1 = __ballot(t == 1);
    __shared__ int w0[4], w1[4];
    __shared__ int base0, base1;
    if (lane == 0) { w0[wid] = __popcll(b0); w1[wid] = __popcll(b1); }
    __syncthreads();
    if (threadIdx.x == 0) {
        base0 = atomicAdd(&cnt[0], w0[0] + w0[1] + w0[2] + w0[3]);
        base1 = atomicAdd(&cnt[1], w1[0] + w1[1] + w1[2] + w1[3]);
    }
    __syncthreads();
    int p0 = 0, p1 = 0;
#pragma unroll
    for (int w = 0; w < 4; ++w) if (w < wid) { p0 += w0[w]; p1 += w1[w]; }
    const unsigned long long ltm = (1ull << lane) - 1ull;
    if (t == 0)      l0[base0 + p0 + __popcll(b0 & ltm)] = i;
    else if (t == 1) l1[base1 + p1 + __popcll(b1 & ltm)] = i;
}

// ---------------- prep: W (D x E, f32) -> Wt (E x D, bf16); also zero cnt ----
__global__ void prep_w_kernel(const float* __restrict__ W0, const float* __restrict__ W1,
                              ushort* __restrict__ Wt0, ushort* __restrict__ Wt1,
                              int* __restrict__ cnt) {
    if (blockIdx.x == 0 && threadIdx.x < 4) cnt[threadIdx.x] = 0;  // runs before compact (stream order)
    int gid = blockIdx.x * 256 + threadIdx.x;   // 65536 total = 2 * 512 * 64
    int t = gid >> 15;
    int rem = gid & 32767;
    int d = rem >> 6, eg = rem & 63;
    const float* W = t ? W1 : W0;
    ushort* Wt = t ? Wt1 : Wt0;
    f32x4 v = *(const f32x4*)(W + d * EE + eg * 4);
#pragma unroll
    for (int j = 0; j < 4; ++j)
        Wt[(size_t)(eg * 4 + j) * DD + d] = f2bf(v[j]);
}

// ---------------- embedding gather for tids >= 2 ----------------
__global__ void emb_gather_kernel(const int* __restrict__ ids, const int* __restrict__ tids,
                                  const float* __restrict__ emb, float* __restrict__ out) {
    int gid = blockIdx.x * 256 + threadIdx.x;   // N*64 total, float4 granularity
    int i = gid >> 6, j = gid & 63;
    if (tids[i] >= 2) {
        ((f32x4*)out)[(size_t)i * 64 + j] = ((const f32x4*)emb)[(size_t)ids[i] * 64 + j];
    }
}

// ---------------- fused gathered-A GEMM for BOTH types in one dispatch ----------
// out[list[r]] = bf16(feats[type_ids[list[r]]]) @ W.  BM=128, BN=256, BK=64.
// 512 threads = 8 waves (4 M x 2 N). blockIdx -> (type, tile) from dynamic counts.
__global__ __launch_bounds__(512, 4) void gemm_gather_kernel(
    const int* __restrict__ l0, const int* __restrict__ l1,
    const int* __restrict__ cntp, const int* __restrict__ type_ids,
    const float* __restrict__ feats0, const float* __restrict__ feats1,
    const ushort* __restrict__ Wt0, const ushort* __restrict__ Wt1,
    float* __restrict__ out) {
    const int cnt0 = cntp[0], cnt1 = cntp[1];
    const int ntile0 = (cnt0 + 127) >> 7;
    const int ntile1 = (cnt1 + 127) >> 7;
    const int b = blockIdx.x;
    const int* list; const float* feats; const ushort* Wt; int cnt, tile;
    if (b < ntile0)                { tile = b;          list = l0; feats = feats0; Wt = Wt0; cnt = cnt0; }
    else if (b < ntile0 + ntile1)  { tile = b - ntile0; list = l1; feats = feats1; Wt = Wt1; cnt = cnt1; }
    else return;
    const int row0 = tile * 128;

    __shared__ char Alds[128 * 64 * 2];   // 16 KB, byte addr row*128 + k*2, XOR swizzled
    __shared__ char Blds[256 * 64 * 2];   // 32 KB, byte addr col*128 + k*2, XOR swizzled

    const int tid = threadIdx.x;
    const int lane = tid & 63, wid = tid >> 6;
    const int wr = wid >> 1, wc = wid & 1;      // wave tile: 32 rows x 128 cols
    const int ln15 = lane & 15, lq = lane >> 4;

    // A gather setup: thread = (row = tid>>2) x (seg = tid&3, 16 f32 each)
    const int ar = tid >> 2, aseg = tid & 3;
    const int rg = row0 + ar;
    int arow = 0;
    if (rg < cnt) arow = type_ids[list[rg]];
    const float* asrc = feats + (size_t)arow * DD + aseg * 16;
    int aw0 = ar * 128 + aseg * 32;
    int aw1 = aw0 + 16;
    aw0 ^= (ar & 7) << 4;
    aw1 ^= (ar & 7) << 4;

    f32x4 acc[2][8] = {};

    for (int k0 = 0; k0 < DD; k0 += 64) {
        // ---- stage A: 16 f32 -> 16 bf16 -> 2x ds_write_b128
        const f32x4* ap = (const f32x4*)(asrc + k0);
        f32x4 v0 = ap[0], v1 = ap[1], v2 = ap[2], v3 = ap[3];
        bf16x8 h0, h1;
        h0[0] = (short)f2bf(v0[0]); h0[1] = (short)f2bf(v0[1]);
        h0[2] = (short)f2bf(v0[2]); h0[3] = (short)f2bf(v0[3]);
        h0[4] = (short)f2bf(v1[0]); h0[5] = (short)f2bf(v1[1]);
        h0[6] = (short)f2bf(v1[2]); h0[7] = (short)f2bf(v1[3]);
        h1[0] = (short)f2bf(v2[0]); h1[1] = (short)f2bf(v2[1]);
        h1[2] = (short)f2bf(v2[2]); h1[3] = (short)f2bf(v2[3]);
        h1[4] = (short)f2bf(v3[0]); h1[5] = (short)f2bf(v3[1]);
        h1[6] = (short)f2bf(v3[2]); h1[7] = (short)f2bf(v3[3]);
        *(bf16x8*)(Alds + aw0) = h0;
        *(bf16x8*)(Alds + aw1) = h1;

        // ---- stage B: 256 cols x 64 k bf16 from Wt (already transposed)
#pragma unroll
        for (int p = 0; p < 4; ++p) {
            int c = p * 512 + tid;
            int col = c >> 3, seg = c & 7;
            bf16x8 bv = *(const bf16x8*)(Wt + col * DD + k0 + seg * 8);
            int addr = col * 128 + seg * 16;
            addr ^= (col & 7) << 4;
            *(bf16x8*)(Blds + addr) = bv;
        }
        __syncthreads();

        // ---- compute: 2 k-halves x (2 M-frags x 8 N-frags)
#pragma unroll
        for (int kh = 0; kh < 2; ++kh) {
            const int kb = kh * 64 + lq * 16;
            int ra0 = wr * 32 + ln15;
            int a0addr = (ra0 * 128 + kb) ^ ((ra0 & 7) << 4);
            int ra1 = ra0 + 16;
            int a1addr = (ra1 * 128 + kb) ^ ((ra1 & 7) << 4);
            bf16x8 a0 = *(const bf16x8*)(Alds + a0addr);
            bf16x8 a1 = *(const bf16x8*)(Alds + a1addr);
#pragma unroll
            for (int ni = 0; ni < 8; ++ni) {
                int col = wc * 128 + ni * 16 + ln15;
                int baddr = (col * 128 + kb) ^ ((col & 7) << 4);
                bf16x8 b = *(const bf16x8*)(Blds + baddr);
                acc[0][ni] = __builtin_amdgcn_mfma_f32_16x16x32_bf16(a0, b, acc[0][ni], 0, 0, 0);
                acc[1][ni] = __builtin_amdgcn_mfma_f32_16x16x32_bf16(a1, b, acc[1][ni], 0, 0, 0);
            }
        }
        __syncthreads();
    }

    // ---- epilogue: scatter rows to out[node]
#pragma unroll
    for (int mi = 0; mi < 2; ++mi) {
        int mbase = row0 + wr * 32 + mi * 16 + lq * 4;
#pragma unroll
        for (int rr = 0; rr < 4; ++rr) {
            int r = mbase + rr;
            if (r < cnt) {
                int nd = list[r];
                float* orow = out + (size_t)nd * EE + wc * 128 + ln15;
#pragma unroll
                for (int ni = 0; ni < 8; ++ni) orow[ni * 16] = acc[mi][ni][rr];
            }
        }
    }
}

extern "C" void kernel_launch(void* const* d_in, const int* in_sizes, int n_in,
                              void* d_out, int out_size, void* d_ws, size_t ws_size,
                              hipStream_t stream) {
    const int*   node_ids  = (const int*)d_in[0];
    const int*   node_tids = (const int*)d_in[1];
    const int*   type_ids  = (const int*)d_in[2];
    const float* feats0    = (const float*)d_in[3];
    const float* feats1    = (const float*)d_in[4];
    const float* W0        = (const float*)d_in[5];
    const float* W1        = (const float*)d_in[6];
    const float* node_emb  = (const float*)d_in[7];
    float* out = (float*)d_out;

    char* ws = (char*)d_ws;
    int* cnt = (int*)ws;                              // 16 B
    int* l0  = (int*)(ws + 16);                       // N ints
    int* l1  = (int*)(ws + 16 + 524288);              // N ints
    ushort* Wt0 = (ushort*)(ws + 16 + 2 * 524288);    // 256 KB
    ushort* Wt1 = Wt0 + DD * EE;                      // 256 KB

    prep_w_kernel<<<256, 256, 0, stream>>>(W0, W1, Wt0, Wt1, cnt);
    compact_kernel<<<512, 256, 0, stream>>>(node_tids, cnt, l0, l1);
    emb_gather_kernel<<<32768, 256, 0, stream>>>(node_ids, node_tids, node_emb, out);
    gemm_gather_kernel<<<2048, 512, 0, stream>>>(l0, l1, cnt, type_ids,
                                                 feats0, feats1, Wt0, Wt1, out);
}